// Round 3
// baseline (4430.913 us; speedup 1.0000x reference)
//
#include <hip/hip_runtime.h>
#include <stdint.h>
#include <math.h>

// ---------------------------------------------------------------------------
// MLGKA layer forward, MI355X (gfx950).
// Attention num/den path in full f32 (den cancellation is ill-conditioned);
// bf16 MFMA only for linear-path GEMMs (W_o, FFN). Workspace: 232 MiB.
// ---------------------------------------------------------------------------

typedef __bf16 bf16x8 __attribute__((ext_vector_type(8)));
typedef float f32x4 __attribute__((ext_vector_type(4)));
typedef float f32x2 __attribute__((ext_vector_type(2)));
typedef unsigned short u16x8 __attribute__((ext_vector_type(8)));
typedef unsigned short u16x4 __attribute__((ext_vector_type(4)));

#define DEV __device__ __forceinline__

DEV unsigned short f2b(float f) {
  union { float f; unsigned int u; } v;
  v.f = f;
  unsigned int u = v.u;
  return (unsigned short)((u + 0x7FFFu + ((u >> 16) & 1u)) >> 16);  // RNE
}
DEV float b2f(unsigned short h) {
  union { unsigned int u; float f; } v;
  v.u = ((unsigned int)h) << 16;
  return v.f;
}

DEV void async16(const void* g, void* l) {
  typedef __attribute__((address_space(1))) unsigned int* gp_t;
  typedef __attribute__((address_space(3))) unsigned int* lp_t;
  __builtin_amdgcn_global_load_lds((gp_t)(g), (lp_t)(l), 16, 0, 0);
}

// ---------------------------------------------------------------------------
// bf16 MFMA core: C[128x128] = A[128xK] * Bt[128xK]^T (m97 pattern).
// ---------------------------------------------------------------------------
template <typename Epi>
DEV void gemm_core(const unsigned short* __restrict__ A,
                   const unsigned short* __restrict__ Bt,
                   int K, int lda, int ldb, Epi epi) {
  __shared__ alignas(16) unsigned short As[128 * 64];
  __shared__ alignas(16) unsigned short Bs[128 * 64];
  const int tid = threadIdx.x;
  const int lane = tid & 63;
  const int wr = ((tid >> 6) >> 1) * 64;
  const int wc = ((tid >> 6) & 1) * 64;
  const int ln = lane & 15;
  const int kq = (lane >> 4) * 8;

  const f32x4 fz = {0.f, 0.f, 0.f, 0.f};
  f32x4 acc[4][4];
#pragma unroll
  for (int i = 0; i < 4; ++i)
#pragma unroll
    for (int j = 0; j < 4; ++j) acc[i][j] = fz;

  for (int kb = 0; kb < K; kb += 64) {
#pragma unroll
    for (int c = 0; c < 4; ++c) {
      int o = (c * 256 + tid) * 16;
      int row = o >> 7;
      int ke = (o & 127) >> 1;
      async16(A + (size_t)row * lda + kb + ke, (void*)(As + (o >> 1)));
      async16(Bt + (size_t)row * ldb + kb + ke, (void*)(Bs + (o >> 1)));
    }
    __syncthreads();
#pragma unroll
    for (int t = 0; t < 2; ++t) {
      const int kk = t * 32 + kq;
      bf16x8 av[4], bv[4];
#pragma unroll
      for (int i = 0; i < 4; ++i)
        av[i] = *(const bf16x8*)(As + (wr + i * 16 + ln) * 64 + kk);
#pragma unroll
      for (int j = 0; j < 4; ++j)
        bv[j] = *(const bf16x8*)(Bs + (wc + j * 16 + ln) * 64 + kk);
#pragma unroll
      for (int i = 0; i < 4; ++i)
#pragma unroll
        for (int j = 0; j < 4; ++j)
          acc[i][j] = __builtin_amdgcn_mfma_f32_16x16x32_bf16(av[i], bv[j], acc[i][j], 0, 0, 0);
    }
    __syncthreads();
  }
  const int rb = (lane >> 4) * 4;
#pragma unroll
  for (int i = 0; i < 4; ++i)
#pragma unroll
    for (int j = 0; j < 4; ++j)
#pragma unroll
      for (int r = 0; r < 4; ++r)
        epi(wr + i * 16 + rb + r, wc + j * 16 + ln, acc[i][j][r]);
}

// y(bf16) = attn @ W_o^T + x
__global__ __launch_bounds__(256) void k_gemm_wo(const unsigned short* __restrict__ A,
                                                 const unsigned short* __restrict__ Bt,
                                                 const float* __restrict__ x,
                                                 unsigned short* __restrict__ y) {
  const int m0 = blockIdx.x * 128, n0 = blockIdx.y * 128;
  gemm_core(A + (size_t)m0 * 2048, Bt + (size_t)n0 * 2048, 2048, 2048, 2048,
            [=](int r, int cc, float v) {
              size_t idx = (size_t)(m0 + r) * 2048 + n0 + cc;
              y[idx] = f2b(v + x[idx]);
            });
}

__global__ __launch_bounds__(256) void k_gemm_gate(const unsigned short* __restrict__ A,
                                                   const unsigned short* __restrict__ Bt,
                                                   unsigned short* __restrict__ gate) {
  const int m0 = blockIdx.x * 128, n0 = blockIdx.y * 128;
  gemm_core(A + (size_t)m0 * 2048, Bt + (size_t)n0 * 2048, 2048, 2048, 2048,
            [=](int r, int cc, float v) {
              gate[(size_t)(m0 + r) * 8192 + n0 + cc] = f2b(v);
            });
}

__global__ __launch_bounds__(256) void k_gemm_up(const unsigned short* __restrict__ A,
                                                 const unsigned short* __restrict__ Bt,
                                                 const unsigned short* __restrict__ gate,
                                                 unsigned short* __restrict__ act) {
  const int m0 = blockIdx.x * 128, n0 = blockIdx.y * 128;
  gemm_core(A + (size_t)m0 * 2048, Bt + (size_t)n0 * 2048, 2048, 2048, 2048,
            [=](int r, int cc, float v) {
              size_t idx = (size_t)(m0 + r) * 8192 + n0 + cc;
              float gv = b2f(gate[idx]);
              float s = v / (1.f + __expf(-v));
              act[idx] = f2b(gv * s);
            });
}

__global__ __launch_bounds__(256) void k_gemm_down(const unsigned short* __restrict__ A,
                                                   const unsigned short* __restrict__ Bt,
                                                   const unsigned short* __restrict__ hbuf,
                                                   float* __restrict__ r2) {
  const int m0 = blockIdx.x * 128, n0 = blockIdx.y * 128;
  gemm_core(A + (size_t)m0 * 8192, Bt + (size_t)n0 * 8192, 8192, 8192, 8192,
            [=](int r, int cc, float v) {
              size_t idx = (size_t)(m0 + r) * 2048 + n0 + cc;
              r2[idx] = v + b2f(hbuf[idx]);
            });
}

// transpose+convert f32 [R][C] -> bf16 [C][R]
__global__ __launch_bounds__(256) void k_tc(const float* __restrict__ in,
                                            unsigned short* __restrict__ out, int R, int C) {
  __shared__ float tile[64][65];
  const int c0 = blockIdx.x * 64, r0 = blockIdx.y * 64;
  const int tid = threadIdx.x;
#pragma unroll
  for (int p = 0; p < 16; ++p) {
    int l = p * 256 + tid;
    int ir = l >> 6, ic = l & 63;
    tile[ic][ir] = in[(size_t)(r0 + ir) * C + c0 + ic];
  }
  __syncthreads();
#pragma unroll
  for (int p = 0; p < 16; ++p) {
    int l = p * 256 + tid;
    int oc = l >> 6, orr = l & 63;
    out[(size_t)(c0 + oc) * R + r0 + orr] = f2b(tile[oc][orr]);
  }
}

// zero z accumulator
__global__ __launch_bounds__(256) void k_zero(float* __restrict__ p, int n) {
  int i = blockIdx.x * 256 + threadIdx.x;
  if (i < n) p[i] = 0.f;
}

// Wq_proj[h] = W_uq[:, h*128:+128] @ omega (f32); same for K-side.
__global__ __launch_bounds__(256) void k_wproj(const float* __restrict__ W_uq,
                                               const float* __restrict__ W_uk,
                                               const float* __restrict__ omega,
                                               float* __restrict__ wqp, float* __restrict__ wkp) {
  const int bi = blockIdx.x;
  const float* W;
  float* outp;
  int ldw, col0;
  if (bi < 16) { W = W_uq; outp = wqp + bi * 4096; ldw = 2048; col0 = bi * 128; }
  else         { W = W_uk; outp = wkp + (bi - 16) * 4096; ldw = 1024; col0 = (bi - 16) * 128; }
  __shared__ float om[128][64];
  const int tid = threadIdx.x;
#pragma unroll
  for (int p = 0; p < 32; ++p) {
    int l = p * 256 + tid;
    om[l >> 6][l & 63] = omega[l];
  }
  __syncthreads();
  const int r = tid >> 2, f0 = (tid & 3) * 16;
  float acc[16];
#pragma unroll
  for (int f = 0; f < 16; ++f) acc[f] = 0.f;
  const float* wrow = W + (size_t)r * ldw + col0;
  for (int d = 0; d < 128; ++d) {
    float w = wrow[d];
#pragma unroll
    for (int f = 0; f < 16; ++f) acc[f] += w * om[d][f0 + f];
  }
#pragma unroll
  for (int f = 0; f < 16; ++f) outp[r * 64 + f0 + f] = acc[f];
}

// c = x @ [W_dq | W_dkv], pure f32. Block: 64 tokens x 128 cols.
__global__ __launch_bounds__(256) void k_cgemm(const float* __restrict__ x,
                                               const float* __restrict__ W_dq,
                                               const float* __restrict__ W_dkv,
                                               float* __restrict__ cbuf) {
  __shared__ float xs[64][65];
  __shared__ float wsh[64][128];
  const int tok0 = blockIdx.x * 64;
  const int tid = threadIdx.x;
  const int ty = tid >> 3, tx = tid & 7;
  const int t0 = ty * 2, c0 = tx * 16;
  float acc[2][16];
#pragma unroll
  for (int i = 0; i < 2; ++i)
#pragma unroll
    for (int e = 0; e < 16; ++e) acc[i][e] = 0.f;
  for (int kb = 0; kb < 2048; kb += 64) {
#pragma unroll
    for (int p = 0; p < 16; ++p) {
      int l = p * 256 + tid;
      int tr = l >> 6, kd = l & 63;
      xs[tr][kd] = x[(size_t)(tok0 + tr) * 2048 + kb + kd];
    }
#pragma unroll
    for (int p = 0; p < 32; ++p) {
      int l = p * 256 + tid;
      int kd = l >> 7, c = l & 127;
      wsh[kd][c] = (c < 64) ? W_dq[(size_t)(kb + kd) * 64 + c]
                            : W_dkv[(size_t)(kb + kd) * 64 + (c - 64)];
    }
    __syncthreads();
    for (int kd = 0; kd < 64; ++kd) {
      float a0 = xs[t0][kd], a1 = xs[t0 + 1][kd];
#pragma unroll
      for (int e = 0; e < 16; ++e) {
        float w = wsh[kd][c0 + e];
        acc[0][e] += a0 * w;
        acc[1][e] += a1 * w;
      }
    }
    __syncthreads();
  }
#pragma unroll
  for (int i = 0; i < 2; ++i)
#pragma unroll
    for (int e = 0; e < 16; ++e)
      cbuf[(size_t)(tok0 + t0 + i) * 128 + c0 + e] = acc[i][e];
}

// phi_k (f32, transposed [bh][f=128][s=4096]) + z accumulation (atomicAdd).
__global__ __launch_bounds__(256) void k_phikz(const float* __restrict__ c,
                                               const float* __restrict__ wkp,
                                               float* __restrict__ phikT,
                                               float* __restrict__ z) {
  const int s0 = blockIdx.x * 64;
  const int bh = blockIdx.y;  // b*8+hkv
  const int b = bh >> 3, hkv = bh & 7;
  __shared__ float ck[64][65];
  __shared__ float wp[64][68];
  const int tid = threadIdx.x;
#pragma unroll
  for (int p = 0; p < 16; ++p) {
    int l = p * 256 + tid;
    int sr = l >> 6, d = l & 63;
    ck[sr][d] = c[(size_t)(b * 4096 + s0 + sr) * 128 + 64 + d];
    wp[sr][d] = wkp[hkv * 4096 + l];
  }
  __syncthreads();
  const int ty = tid & 31, fx = tid >> 5;
  const int f0 = fx * 8, r0 = ty * 2;
  float pr[2][8];
#pragma unroll
  for (int rr = 0; rr < 2; ++rr)
#pragma unroll
    for (int ff = 0; ff < 8; ++ff) pr[rr][ff] = 0.f;
  for (int d = 0; d < 64; ++d) {
    f32x4 w0 = *(const f32x4*)&wp[d][f0];
    f32x4 w1 = *(const f32x4*)&wp[d][f0 + 4];
    float c0v = ck[r0][d], c1v = ck[r0 + 1][d];
#pragma unroll
    for (int e = 0; e < 4; ++e) {
      pr[0][e] += c0v * w0[e]; pr[0][4 + e] += c0v * w1[e];
      pr[1][e] += c1v * w0[e]; pr[1][4 + e] += c1v * w1[e];
    }
  }
  float* obase = phikT + (size_t)bh * 524288 + s0 + r0;
  float zc[8], zs2[8];
#pragma unroll
  for (int ff = 0; ff < 8; ++ff) {
    float sv0, cv0, sv1, cv1;
    __sincosf(pr[0][ff], &sv0, &cv0);
    __sincosf(pr[1][ff], &sv1, &cv1);
    float c0 = cv0 * 0.125f, c1 = cv1 * 0.125f;
    float s0v = sv0 * 0.125f, s1v = sv1 * 0.125f;
    f32x2 co; co[0] = c0; co[1] = c1;
    f32x2 si; si[0] = s0v; si[1] = s1v;
    *(f32x2*)(obase + (size_t)(f0 + ff) * 4096) = co;
    *(f32x2*)(obase + (size_t)(64 + f0 + ff) * 4096) = si;
    zc[ff] = c0 + c1;
    zs2[ff] = s0v + s1v;
  }
#pragma unroll
  for (int off = 16; off; off >>= 1) {
#pragma unroll
    for (int ff = 0; ff < 8; ++ff) {
      zc[ff] += __shfl_down(zc[ff], off);
      zs2[ff] += __shfl_down(zs2[ff], off);
    }
  }
  if (ty == 0) {
#pragma unroll
    for (int ff = 0; ff < 8; ++ff) {
      atomicAdd(&z[bh * 128 + f0 + ff], zc[ff]);
      atomicAdd(&z[bh * 128 + 64 + f0 + ff], zs2[ff]);
    }
  }
}

// v = c_kv @ W_uv (f32), transposed [bh][d=128][s=4096].
__global__ __launch_bounds__(256) void k_vf(const float* __restrict__ c,
                                            const float* __restrict__ W_uv,
                                            float* __restrict__ vT) {
  const int s0 = blockIdx.x * 64;
  const int bh = blockIdx.y;
  const int b = bh >> 3, hkv = bh & 7;
  __shared__ float ck[64][65];
  __shared__ float wv[64][132];
  const int tid = threadIdx.x;
#pragma unroll
  for (int p = 0; p < 16; ++p) {
    int l = p * 256 + tid;
    int sr = l >> 6, d = l & 63;
    ck[sr][d] = c[(size_t)(b * 4096 + s0 + sr) * 128 + 64 + d];
  }
#pragma unroll
  for (int p = 0; p < 32; ++p) {
    int l = p * 256 + tid;
    int rr = l >> 7, d = l & 127;
    wv[rr][d] = W_uv[(size_t)rr * 1024 + hkv * 128 + d];
  }
  __syncthreads();
  const int ty = tid & 15, tx = tid >> 4;
  const int r0 = ty * 4, d0 = tx * 8;
  float acc[4][8];
#pragma unroll
  for (int rr = 0; rr < 4; ++rr)
#pragma unroll
    for (int dd = 0; dd < 8; ++dd) acc[rr][dd] = 0.f;
  for (int kk = 0; kk < 64; ++kk) {
    f32x4 w0 = *(const f32x4*)&wv[kk][d0];
    f32x4 w1 = *(const f32x4*)&wv[kk][d0 + 4];
    float cv[4];
#pragma unroll
    for (int rr = 0; rr < 4; ++rr) cv[rr] = ck[r0 + rr][kk];
#pragma unroll
    for (int rr = 0; rr < 4; ++rr)
#pragma unroll
      for (int e = 0; e < 4; ++e) {
        acc[rr][e] += cv[rr] * w0[e];
        acc[rr][4 + e] += cv[rr] * w1[e];
      }
  }
  float* obase = vT + (size_t)bh * 524288 + s0 + r0;
#pragma unroll
  for (int dd = 0; dd < 8; ++dd) {
    f32x4 pv;
    pv[0] = acc[0][dd]; pv[1] = acc[1][dd]; pv[2] = acc[2][dd]; pv[3] = acc[3][dd];
    *(f32x4*)(obase + (size_t)(d0 + dd) * 4096) = pv;
  }
}

// kv[f][d] = sum_s phi_k[s,f]*v[s,d], f32. grid (4 f-quarters, 32 bh).
__global__ __launch_bounds__(256) void k_kvf(const float* __restrict__ phikT,
                                             const float* __restrict__ vT,
                                             float* __restrict__ kvf) {
  const int fq = blockIdx.x, bh = blockIdx.y;
  const float* pT = phikT + (size_t)bh * 524288 + (size_t)fq * 32 * 4096;
  const float* vB = vT + (size_t)bh * 524288;
  __shared__ float phis2[64][36];
  __shared__ float vs2[64][132];
  const int tid = threadIdx.x;
  const int fg = tid >> 5, dg = tid & 31;
  float acc[4][4];
#pragma unroll
  for (int i = 0; i < 4; ++i)
#pragma unroll
    for (int j = 0; j < 4; ++j) acc[i][j] = 0.f;
  for (int ss = 0; ss < 4096; ss += 64) {
#pragma unroll
    for (int p = 0; p < 8; ++p) {
      int l = p * 256 + tid;
      int fi = l >> 6, si = l & 63;
      phis2[si][fi] = pT[(size_t)fi * 4096 + ss + si];
    }
#pragma unroll
    for (int p = 0; p < 32; ++p) {
      int l = p * 256 + tid;
      int di = l >> 6, si = l & 63;
      vs2[si][di] = vB[(size_t)di * 4096 + ss + si];
    }
    __syncthreads();
    for (int si = 0; si < 64; ++si) {
      f32x4 p4 = *(const f32x4*)&phis2[si][fg * 4];
      f32x4 v4 = *(const f32x4*)&vs2[si][dg * 4];
#pragma unroll
      for (int i = 0; i < 4; ++i)
#pragma unroll
        for (int j = 0; j < 4; ++j) acc[i][j] += p4[i] * v4[j];
    }
    __syncthreads();
  }
#pragma unroll
  for (int i = 0; i < 4; ++i)
#pragma unroll
    for (int j = 0; j < 4; ++j)
      kvf[((size_t)bh * 128 + fq * 32 + fg * 4 + i) * 128 + dg * 4 + j] = acc[i][j];
}

// Fused: phi_q (f32, LDS) + den (f32) + num (f32 vs kv) + divide -> attn bf16.
// grid (64 s-tiles, 4 d-quarters, 64 bh).
__global__ __launch_bounds__(256) void k_attn(const float* __restrict__ c,
                                              const float* __restrict__ wqp,
                                              const float* __restrict__ zb,
                                              const float* __restrict__ kvf,
                                              unsigned short* __restrict__ attn) {
  const int s0 = blockIdx.x * 64;
  const int d0b = blockIdx.y * 32;
  const int bh = blockIdx.z;  // b*16+h
  const int b = bh >> 4, h = bh & 15;
  const int bhk = (b << 3) + (h >> 1);
  __shared__ float phl[64][132];
  __shared__ float U[6176];  // cq[32][65] + wq[64*64]  |  kvl[128][32]
  __shared__ float zl[128];
  __shared__ float denl[64];
  float (*cq)[65] = (float(*)[65])(void*)U;
  float* wq = U + 2080;
  float (*kvl)[32] = (float(*)[32])(void*)U;
  const int tid = threadIdx.x;
  if (tid < 128) zl[tid] = zb[bhk * 128 + tid];
#pragma unroll
  for (int p = 0; p < 16; ++p) {
    int l = p * 256 + tid;
    wq[l] = wqp[h * 4096 + l];
  }
  const int fx = tid & 7, ty = tid >> 3;
  const int f0 = fx * 8, r0 = ty * 2;
  float pr[2][8];
#pragma unroll
  for (int rr = 0; rr < 2; ++rr)
#pragma unroll
    for (int ff = 0; ff < 8; ++ff) pr[rr][ff] = 0.f;
  for (int half = 0; half < 2; ++half) {
    __syncthreads();
#pragma unroll
    for (int p = 0; p < 8; ++p) {
      int l = p * 256 + tid;
      int sr = l >> 6, dd = l & 63;
      cq[sr][dd] = c[(size_t)(b * 4096 + s0 + half * 32 + sr) * 128 + dd];
    }
    __syncthreads();
    if ((ty >> 4) == half) {
      const int rl = r0 & 31;
      for (int d = 0; d < 64; ++d) {
        f32x4 w0 = *(const f32x4*)(wq + d * 64 + f0);
        f32x4 w1 = *(const f32x4*)(wq + d * 64 + f0 + 4);
        float c0v = cq[rl][d], c1v = cq[rl + 1][d];
#pragma unroll
        for (int e = 0; e < 4; ++e) {
          pr[0][e] += c0v * w0[e]; pr[0][4 + e] += c0v * w1[e];
          pr[1][e] += c1v * w0[e]; pr[1][4 + e] += c1v * w1[e];
        }
      }
    }
  }
#pragma unroll
  for (int rr = 0; rr < 2; ++rr)
#pragma unroll
    for (int ff = 0; ff < 8; ++ff) {
      float sv, cv;
      __sincosf(pr[rr][ff], &sv, &cv);
      phl[r0 + rr][f0 + ff] = cv * 0.125f;
      phl[r0 + rr][64 + f0 + ff] = sv * 0.125f;
    }
  __syncthreads();
  // den
  const int sD = tid >> 2, qD = tid & 3;
  float dpart = 0.f;
#pragma unroll
  for (int k = 0; k < 32; k += 4) {
    f32x4 pv = *(const f32x4*)&phl[sD][qD * 32 + k];
    f32x4 zv = *(const f32x4*)&zl[qD * 32 + k];
    dpart += pv[0] * zv[0] + pv[1] * zv[1] + pv[2] * zv[2] + pv[3] * zv[3];
  }
  dpart += __shfl_down(dpart, 2);
  dpart += __shfl_down(dpart, 1);
  if (qD == 0) denl[sD] = dpart + 1e-6f;
  __syncthreads();
  // kv tile
#pragma unroll
  for (int p = 0; p < 16; ++p) {
    int l = p * 256 + tid;
    kvl[l >> 5][l & 31] = kvf[(size_t)bhk * 16384 + (size_t)(l >> 5) * 128 + d0b + (l & 31)];
  }
  __syncthreads();
  // num
  const int sg = tid >> 3, dq = tid & 7;
  const int sa = sg * 2, d0 = dq * 4;
  f32x4 acc0 = {0.f, 0.f, 0.f, 0.f}, acc1 = acc0;
  for (int f = 0; f < 128; f += 2) {
    f32x2 pa = *(const f32x2*)&phl[sa][f];
    f32x2 pb = *(const f32x2*)&phl[sa + 1][f];
    f32x4 k0 = *(const f32x4*)&kvl[f][d0];
    f32x4 k1 = *(const f32x4*)&kvl[f + 1][d0];
#pragma unroll
    for (int j = 0; j < 4; ++j) {
      acc0[j] += pa[0] * k0[j] + pa[1] * k1[j];
      acc1[j] += pb[0] * k0[j] + pb[1] * k1[j];
    }
  }
  const float da = denl[sa], db = denl[sa + 1];
  const size_t ta = (size_t)(b * 4096 + s0 + sa) * 2048 + h * 128 + d0b + d0;
  u16x4 oa, ob;
#pragma unroll
  for (int j = 0; j < 4; ++j) {
    oa[j] = f2b(acc0[j] / da);
    ob[j] = f2b(acc1[j] / db);
  }
  *(u16x4*)(attn + ta) = oa;
  *(u16x4*)(attn + ta + 2048) = ob;
}

// LayerNorm bf16->bf16 (ln1)
__global__ __launch_bounds__(256) void k_ln_b2b(const unsigned short* __restrict__ in,
                                                const float* __restrict__ g,
                                                const float* __restrict__ bb,
                                                unsigned short* __restrict__ ob) {
  const int row = blockIdx.x;
  const unsigned short* xr = in + (size_t)row * 2048;
  float vals[8], s = 0.f, ss = 0.f;
#pragma unroll
  for (int i = 0; i < 8; ++i) {
    float v = b2f(xr[i * 256 + threadIdx.x]);
    vals[i] = v; s += v; ss += v * v;
  }
#pragma unroll
  for (int off = 32; off; off >>= 1) { s += __shfl_down(s, off); ss += __shfl_down(ss, off); }
  __shared__ float red[8];
  const int wave = threadIdx.x >> 6;
  if ((threadIdx.x & 63) == 0) { red[wave * 2] = s; red[wave * 2 + 1] = ss; }
  __syncthreads();
  float S = red[0] + red[2] + red[4] + red[6];
  float SS = red[1] + red[3] + red[5] + red[7];
  float mu = S * (1.f / 2048.f);
  float var = SS * (1.f / 2048.f) - mu * mu;
  float inv = rsqrtf(var + 1e-5f);
#pragma unroll
  for (int i = 0; i < 8; ++i) {
    int col = i * 256 + threadIdx.x;
    ob[(size_t)row * 2048 + col] = f2b((vals[i] - mu) * inv * g[col] + bb[col]);
  }
}

// LayerNorm f32->f32 (ln2)
__global__ __launch_bounds__(256) void k_ln_f2f(const float* __restrict__ in,
                                                const float* __restrict__ g,
                                                const float* __restrict__ bb,
                                                float* __restrict__ of) {
  const int row = blockIdx.x;
  const float* xr = in + (size_t)row * 2048;
  float vals[8], s = 0.f, ss = 0.f;
#pragma unroll
  for (int i = 0; i < 8; ++i) {
    float v = xr[i * 256 + threadIdx.x];
    vals[i] = v; s += v; ss += v * v;
  }
#pragma unroll
  for (int off = 32; off; off >>= 1) { s += __shfl_down(s, off); ss += __shfl_down(ss, off); }
  __shared__ float red[8];
  const int wave = threadIdx.x >> 6;
  if ((threadIdx.x & 63) == 0) { red[wave * 2] = s; red[wave * 2 + 1] = ss; }
  __syncthreads();
  float S = red[0] + red[2] + red[4] + red[6];
  float SS = red[1] + red[3] + red[5] + red[7];
  float mu = S * (1.f / 2048.f);
  float var = SS * (1.f / 2048.f) - mu * mu;
  float inv = rsqrtf(var + 1e-5f);
#pragma unroll
  for (int i = 0; i < 8; ++i) {
    int col = i * 256 + threadIdx.x;
    of[(size_t)row * 2048 + col] = (vals[i] - mu) * inv * g[col] + bb[col];
  }
}

// ---------------------------------------------------------------------------
extern "C" void kernel_launch(void* const* d_in, const int* in_sizes, int n_in,
                              void* d_out, int out_size, void* d_ws, size_t ws_size,
                              hipStream_t stream) {
  (void)in_sizes; (void)n_in; (void)out_size; (void)ws_size;
  const float* x     = (const float*)d_in[0];
  const float* W_dq  = (const float*)d_in[1];
  const float* W_uq  = (const float*)d_in[2];
  const float* W_dkv = (const float*)d_in[3];
  const float* W_uk  = (const float*)d_in[4];
  const float* W_uv  = (const float*)d_in[5];
  const float* omega = (const float*)d_in[6];
  const float* W_o   = (const float*)d_in[7];
  const float* ln1g  = (const float*)d_in[8];
  const float* ln1b  = (const float*)d_in[9];
  const float* gateW = (const float*)d_in[10];
  const float* upW   = (const float*)d_in[11];
  const float* downW = (const float*)d_in[12];
  const float* ln2g  = (const float*)d_in[13];
  const float* ln2b  = (const float*)d_in[14];
  float* out = (float*)d_out;

  // Workspace (232 MiB, liveness-overlaid):
  // R0 [0,64M):    phikTf(f32) -> gatet|upt
  // R1 [64,128M):  vTf(f32) -> attn(bf16) -> hb(bf16)
  // R2 [128,192M): cbuf/wqp/wkp/zb/kvf -> y(bf16) -> gatec|actc, r2c
  // R3 [192,200M): wot   R4 [200,232M): downt
  char* w = (char*)d_ws;
  float*          phikTf = (float*)(w);
  float*          vTf    = (float*)(w + 67108864);
  unsigned short* attn   = (unsigned short*)(w + 67108864);
  unsigned short* hb     = (unsigned short*)(w + 67108864);
  unsigned short* gatet  = (unsigned short*)(w);
  unsigned short* upt    = (unsigned short*)(w + 33554432);
  char* C = w + 134217728;
  float*          cbuf = (float*)(C);
  float*          wqp  = (float*)(C + 8388608);
  float*          wkp  = (float*)(C + 8650752);
  float*          zb   = (float*)(C + 8781824);
  float*          kvf  = (float*)(C + 8798208);
  unsigned short* y    = (unsigned short*)(C);
  unsigned short* gatec = (unsigned short*)(C);
  unsigned short* actc  = (unsigned short*)(C + 33554432);
  float*          r2c   = (float*)(C);
  unsigned short* wot   = (unsigned short*)(w + 201326592);
  unsigned short* downt = (unsigned short*)(w + 209715200);

  // phase 0: prep
  k_zero<<<16, 256, 0, stream>>>(zb, 4096);
  k_wproj<<<24, 256, 0, stream>>>(W_uq, W_uk, omega, wqp, wkp);
  k_tc<<<dim3(32, 32), 256, 0, stream>>>(W_o, wot, 2048, 2048);

  // phase 1: latents (f32)
  k_cgemm<<<256, 256, 0, stream>>>(x, W_dq, W_dkv, cbuf);

  // phase 2: phi_k + z, v (f32)
  k_phikz<<<dim3(64, 32), 256, 0, stream>>>(cbuf, wkp, phikTf, zb);
  k_vf<<<dim3(64, 32), 256, 0, stream>>>(cbuf, W_uv, vTf);

  // phase 3: kv (f32), fused phi_q/den/num -> attn(bf16)
  k_kvf<<<dim3(4, 32), 256, 0, stream>>>(phikTf, vTf, kvf);
  k_attn<<<dim3(64, 4, 64), 256, 0, stream>>>(cbuf, wqp, zb, kvf, attn);

  // phase 4: W_o + residual + LN1
  k_gemm_wo<<<dim3(128, 16), 256, 0, stream>>>(attn, wot, x, y);
  k_ln_b2b<<<16384, 256, 0, stream>>>(y, ln1g, ln1b, hb);

  // phase 5: FFN weight transposes into freed regions
  k_tc<<<dim3(128, 32), 256, 0, stream>>>(gateW, gatet, 2048, 8192);
  k_tc<<<dim3(128, 32), 256, 0, stream>>>(upW, upt, 2048, 8192);
  k_tc<<<dim3(32, 128), 256, 0, stream>>>(downW, downt, 8192, 2048);

  // phase 6: FFN in 8 chunks of 2048 rows
  for (int cix = 0; cix < 8; ++cix) {
    const unsigned short* hbc = hb + (size_t)cix * 2048 * 2048;
    float* outc = out + (size_t)cix * 2048 * 2048;
    k_gemm_gate<<<dim3(16, 64), 256, 0, stream>>>(hbc, gatet, gatec);
    k_gemm_up<<<dim3(16, 64), 256, 0, stream>>>(hbc, upt, gatec, actc);
    k_gemm_down<<<dim3(16, 16), 256, 0, stream>>>(actc, downt, hbc, r2c);
    k_ln_f2f<<<2048, 256, 0, stream>>>(r2c, ln2g, ln2b, outc);
  }
}

// Round 4
// 3761.891 us; speedup vs baseline: 1.1778x; 1.1778x over previous
//
#include <hip/hip_runtime.h>
#include <stdint.h>
#include <math.h>

// ---------------------------------------------------------------------------
// MLGKA layer forward, MI355X (gfx950).
// Attention num/den path in full f32; bf16 MFMA for linear-path GEMMs
// (W_o, FFN). Workspace: 232 MiB, liveness-overlaid.
// R4: k_attn merged d-quarters (no 4x phi_q recompute); kvf 512 blocks;
// FFN: no gate buffer (RMW epilogue), down writes out directly, LN2 in-place.
// ---------------------------------------------------------------------------

typedef __bf16 bf16x8 __attribute__((ext_vector_type(8)));
typedef float f32x4 __attribute__((ext_vector_type(4)));
typedef float f32x2 __attribute__((ext_vector_type(2)));
typedef unsigned short u16x8 __attribute__((ext_vector_type(8)));
typedef unsigned short u16x4 __attribute__((ext_vector_type(4)));

#define DEV __device__ __forceinline__

DEV unsigned short f2b(float f) {
  union { float f; unsigned int u; } v;
  v.f = f;
  unsigned int u = v.u;
  return (unsigned short)((u + 0x7FFFu + ((u >> 16) & 1u)) >> 16);  // RNE
}
DEV float b2f(unsigned short h) {
  union { unsigned int u; float f; } v;
  v.u = ((unsigned int)h) << 16;
  return v.f;
}

DEV void async16(const void* g, void* l) {
  typedef __attribute__((address_space(1))) unsigned int* gp_t;
  typedef __attribute__((address_space(3))) unsigned int* lp_t;
  __builtin_amdgcn_global_load_lds((gp_t)(g), (lp_t)(l), 16, 0, 0);
}

// ---------------------------------------------------------------------------
// bf16 MFMA core: C[128x128] = A[128xK] * Bt[128xK]^T (m97 pattern).
// ---------------------------------------------------------------------------
template <typename Epi>
DEV void gemm_core(const unsigned short* __restrict__ A,
                   const unsigned short* __restrict__ Bt,
                   int K, int lda, int ldb, Epi epi) {
  __shared__ alignas(16) unsigned short As[128 * 64];
  __shared__ alignas(16) unsigned short Bs[128 * 64];
  const int tid = threadIdx.x;
  const int lane = tid & 63;
  const int wr = ((tid >> 6) >> 1) * 64;
  const int wc = ((tid >> 6) & 1) * 64;
  const int ln = lane & 15;
  const int kq = (lane >> 4) * 8;

  const f32x4 fz = {0.f, 0.f, 0.f, 0.f};
  f32x4 acc[4][4];
#pragma unroll
  for (int i = 0; i < 4; ++i)
#pragma unroll
    for (int j = 0; j < 4; ++j) acc[i][j] = fz;

  for (int kb = 0; kb < K; kb += 64) {
#pragma unroll
    for (int c = 0; c < 4; ++c) {
      int o = (c * 256 + tid) * 16;
      int row = o >> 7;
      int ke = (o & 127) >> 1;
      async16(A + (size_t)row * lda + kb + ke, (void*)(As + (o >> 1)));
      async16(Bt + (size_t)row * ldb + kb + ke, (void*)(Bs + (o >> 1)));
    }
    __syncthreads();
#pragma unroll
    for (int t = 0; t < 2; ++t) {
      const int kk = t * 32 + kq;
      bf16x8 av[4], bv[4];
#pragma unroll
      for (int i = 0; i < 4; ++i)
        av[i] = *(const bf16x8*)(As + (wr + i * 16 + ln) * 64 + kk);
#pragma unroll
      for (int j = 0; j < 4; ++j)
        bv[j] = *(const bf16x8*)(Bs + (wc + j * 16 + ln) * 64 + kk);
#pragma unroll
      for (int i = 0; i < 4; ++i)
#pragma unroll
        for (int j = 0; j < 4; ++j)
          acc[i][j] = __builtin_amdgcn_mfma_f32_16x16x32_bf16(av[i], bv[j], acc[i][j], 0, 0, 0);
    }
    __syncthreads();
  }
  const int rb = (lane >> 4) * 4;
#pragma unroll
  for (int i = 0; i < 4; ++i)
#pragma unroll
    for (int j = 0; j < 4; ++j)
#pragma unroll
      for (int r = 0; r < 4; ++r)
        epi(wr + i * 16 + rb + r, wc + j * 16 + ln, acc[i][j][r]);
}

// y(bf16) = attn @ W_o^T + x
__global__ __launch_bounds__(256) void k_gemm_wo(const unsigned short* __restrict__ A,
                                                 const unsigned short* __restrict__ Bt,
                                                 const float* __restrict__ x,
                                                 unsigned short* __restrict__ y) {
  const int m0 = blockIdx.x * 128, n0 = blockIdx.y * 128;
  gemm_core(A + (size_t)m0 * 2048, Bt + (size_t)n0 * 2048, 2048, 2048, 2048,
            [=](int r, int cc, float v) {
              size_t idx = (size_t)(m0 + r) * 2048 + n0 + cc;
              y[idx] = f2b(v + x[idx]);
            });
}

// act = silu(h @ upW) (bf16)
__global__ __launch_bounds__(256) void k_gemm_up2(const unsigned short* __restrict__ A,
                                                  const unsigned short* __restrict__ Bt,
                                                  unsigned short* __restrict__ act) {
  const int m0 = blockIdx.x * 128, n0 = blockIdx.y * 128;
  gemm_core(A + (size_t)m0 * 2048, Bt + (size_t)n0 * 2048, 2048, 2048, 2048,
            [=](int r, int cc, float v) {
              float s = v / (1.f + __expf(-v));
              act[(size_t)(m0 + r) * 8192 + n0 + cc] = f2b(s);
            });
}

// act *= (h @ gateW)   (RMW epilogue; act holds silu(up))
__global__ __launch_bounds__(256) void k_gemm_gatem(const unsigned short* __restrict__ A,
                                                    const unsigned short* __restrict__ Bt,
                                                    unsigned short* act) {
  const int m0 = blockIdx.x * 128, n0 = blockIdx.y * 128;
  gemm_core(A + (size_t)m0 * 2048, Bt + (size_t)n0 * 2048, 2048, 2048, 2048,
            [=](int r, int cc, float v) {
              size_t idx = (size_t)(m0 + r) * 8192 + n0 + cc;
              act[idx] = f2b(v * b2f(act[idx]));
            });
}

// outc(f32) = act @ downW^T + h
__global__ __launch_bounds__(256) void k_gemm_down2(const unsigned short* __restrict__ A,
                                                    const unsigned short* __restrict__ Bt,
                                                    const unsigned short* __restrict__ hbuf,
                                                    float* __restrict__ outc) {
  const int m0 = blockIdx.x * 128, n0 = blockIdx.y * 128;
  gemm_core(A + (size_t)m0 * 8192, Bt + (size_t)n0 * 8192, 8192, 8192, 8192,
            [=](int r, int cc, float v) {
              size_t idx = (size_t)(m0 + r) * 2048 + n0 + cc;
              outc[idx] = v + b2f(hbuf[idx]);
            });
}

// transpose+convert f32 [R][C] -> bf16 [C][R]
__global__ __launch_bounds__(256) void k_tc(const float* __restrict__ in,
                                            unsigned short* __restrict__ out, int R, int C) {
  __shared__ float tile[64][65];
  const int c0 = blockIdx.x * 64, r0 = blockIdx.y * 64;
  const int tid = threadIdx.x;
#pragma unroll
  for (int p = 0; p < 16; ++p) {
    int l = p * 256 + tid;
    int ir = l >> 6, ic = l & 63;
    tile[ic][ir] = in[(size_t)(r0 + ir) * C + c0 + ic];
  }
  __syncthreads();
#pragma unroll
  for (int p = 0; p < 16; ++p) {
    int l = p * 256 + tid;
    int oc = l >> 6, orr = l & 63;
    out[(size_t)(c0 + oc) * R + r0 + orr] = f2b(tile[oc][orr]);
  }
}

__global__ __launch_bounds__(256) void k_zero(float* __restrict__ p, int n) {
  int i = blockIdx.x * 256 + threadIdx.x;
  if (i < n) p[i] = 0.f;
}

// Wq_proj[h] = W_uq[:, h*128:+128] @ omega (f32); same for K-side.
__global__ __launch_bounds__(256) void k_wproj(const float* __restrict__ W_uq,
                                               const float* __restrict__ W_uk,
                                               const float* __restrict__ omega,
                                               float* __restrict__ wqp, float* __restrict__ wkp) {
  const int bi = blockIdx.x;
  const float* W;
  float* outp;
  int ldw, col0;
  if (bi < 16) { W = W_uq; outp = wqp + bi * 4096; ldw = 2048; col0 = bi * 128; }
  else         { W = W_uk; outp = wkp + (bi - 16) * 4096; ldw = 1024; col0 = (bi - 16) * 128; }
  __shared__ float om[128][64];
  const int tid = threadIdx.x;
#pragma unroll
  for (int p = 0; p < 32; ++p) {
    int l = p * 256 + tid;
    om[l >> 6][l & 63] = omega[l];
  }
  __syncthreads();
  const int r = tid >> 2, f0 = (tid & 3) * 16;
  float acc[16];
#pragma unroll
  for (int f = 0; f < 16; ++f) acc[f] = 0.f;
  const float* wrow = W + (size_t)r * ldw + col0;
  for (int d = 0; d < 128; ++d) {
    float w = wrow[d];
#pragma unroll
    for (int f = 0; f < 16; ++f) acc[f] += w * om[d][f0 + f];
  }
#pragma unroll
  for (int f = 0; f < 16; ++f) outp[r * 64 + f0 + f] = acc[f];
}

// c = x @ [W_dq | W_dkv], pure f32. Block: 64 tokens x 128 cols.
__global__ __launch_bounds__(256) void k_cgemm(const float* __restrict__ x,
                                               const float* __restrict__ W_dq,
                                               const float* __restrict__ W_dkv,
                                               float* __restrict__ cbuf) {
  __shared__ float xs[64][65];
  __shared__ float wsh[64][128];
  const int tok0 = blockIdx.x * 64;
  const int tid = threadIdx.x;
  const int ty = tid >> 3, tx = tid & 7;
  const int t0 = ty * 2, c0 = tx * 16;
  float acc[2][16];
#pragma unroll
  for (int i = 0; i < 2; ++i)
#pragma unroll
    for (int e = 0; e < 16; ++e) acc[i][e] = 0.f;
  for (int kb = 0; kb < 2048; kb += 64) {
#pragma unroll
    for (int p = 0; p < 16; ++p) {
      int l = p * 256 + tid;
      int tr = l >> 6, kd = l & 63;
      xs[tr][kd] = x[(size_t)(tok0 + tr) * 2048 + kb + kd];
    }
#pragma unroll
    for (int p = 0; p < 32; ++p) {
      int l = p * 256 + tid;
      int kd = l >> 7, c = l & 127;
      wsh[kd][c] = (c < 64) ? W_dq[(size_t)(kb + kd) * 64 + c]
                            : W_dkv[(size_t)(kb + kd) * 64 + (c - 64)];
    }
    __syncthreads();
    for (int kd = 0; kd < 64; ++kd) {
      float a0 = xs[t0][kd], a1 = xs[t0 + 1][kd];
#pragma unroll
      for (int e = 0; e < 16; ++e) {
        float w = wsh[kd][c0 + e];
        acc[0][e] += a0 * w;
        acc[1][e] += a1 * w;
      }
    }
    __syncthreads();
  }
#pragma unroll
  for (int i = 0; i < 2; ++i)
#pragma unroll
    for (int e = 0; e < 16; ++e)
      cbuf[(size_t)(tok0 + t0 + i) * 128 + c0 + e] = acc[i][e];
}

// phi_k (f32, transposed [bh][f=128][s=4096]) + z accumulation (atomicAdd).
__global__ __launch_bounds__(256) void k_phikz(const float* __restrict__ c,
                                               const float* __restrict__ wkp,
                                               float* __restrict__ phikT,
                                               float* __restrict__ z) {
  const int s0 = blockIdx.x * 64;
  const int bh = blockIdx.y;  // b*8+hkv
  const int b = bh >> 3, hkv = bh & 7;
  __shared__ float ck[64][65];
  __shared__ float wp[64][68];
  const int tid = threadIdx.x;
#pragma unroll
  for (int p = 0; p < 16; ++p) {
    int l = p * 256 + tid;
    int sr = l >> 6, d = l & 63;
    ck[sr][d] = c[(size_t)(b * 4096 + s0 + sr) * 128 + 64 + d];
    wp[sr][d] = wkp[hkv * 4096 + l];
  }
  __syncthreads();
  const int ty = tid & 31, fx = tid >> 5;
  const int f0 = fx * 8, r0 = ty * 2;
  float pr[2][8];
#pragma unroll
  for (int rr = 0; rr < 2; ++rr)
#pragma unroll
    for (int ff = 0; ff < 8; ++ff) pr[rr][ff] = 0.f;
  for (int d = 0; d < 64; ++d) {
    f32x4 w0 = *(const f32x4*)&wp[d][f0];
    f32x4 w1 = *(const f32x4*)&wp[d][f0 + 4];
    float c0v = ck[r0][d], c1v = ck[r0 + 1][d];
#pragma unroll
    for (int e = 0; e < 4; ++e) {
      pr[0][e] += c0v * w0[e]; pr[0][4 + e] += c0v * w1[e];
      pr[1][e] += c1v * w0[e]; pr[1][4 + e] += c1v * w1[e];
    }
  }
  float* obase = phikT + (size_t)bh * 524288 + s0 + r0;
  float zc[8], zs2[8];
#pragma unroll
  for (int ff = 0; ff < 8; ++ff) {
    float sv0, cv0, sv1, cv1;
    __sincosf(pr[0][ff], &sv0, &cv0);
    __sincosf(pr[1][ff], &sv1, &cv1);
    float c0 = cv0 * 0.125f, c1 = cv1 * 0.125f;
    float s0v = sv0 * 0.125f, s1v = sv1 * 0.125f;
    f32x2 co; co[0] = c0; co[1] = c1;
    f32x2 si; si[0] = s0v; si[1] = s1v;
    *(f32x2*)(obase + (size_t)(f0 + ff) * 4096) = co;
    *(f32x2*)(obase + (size_t)(64 + f0 + ff) * 4096) = si;
    zc[ff] = c0 + c1;
    zs2[ff] = s0v + s1v;
  }
#pragma unroll
  for (int off = 16; off; off >>= 1) {
#pragma unroll
    for (int ff = 0; ff < 8; ++ff) {
      zc[ff] += __shfl_down(zc[ff], off);
      zs2[ff] += __shfl_down(zs2[ff], off);
    }
  }
  if (ty == 0) {
#pragma unroll
    for (int ff = 0; ff < 8; ++ff) {
      atomicAdd(&z[bh * 128 + f0 + ff], zc[ff]);
      atomicAdd(&z[bh * 128 + 64 + f0 + ff], zs2[ff]);
    }
  }
}

// v = c_kv @ W_uv (f32), transposed [bh][d=128][s=4096].
__global__ __launch_bounds__(256) void k_vf(const float* __restrict__ c,
                                            const float* __restrict__ W_uv,
                                            float* __restrict__ vT) {
  const int s0 = blockIdx.x * 64;
  const int bh = blockIdx.y;
  const int b = bh >> 3, hkv = bh & 7;
  __shared__ float ck[64][65];
  __shared__ float wv[64][132];
  const int tid = threadIdx.x;
#pragma unroll
  for (int p = 0; p < 16; ++p) {
    int l = p * 256 + tid;
    int sr = l >> 6, d = l & 63;
    ck[sr][d] = c[(size_t)(b * 4096 + s0 + sr) * 128 + 64 + d];
  }
#pragma unroll
  for (int p = 0; p < 32; ++p) {
    int l = p * 256 + tid;
    int rr = l >> 7, d = l & 127;
    wv[rr][d] = W_uv[(size_t)rr * 1024 + hkv * 128 + d];
  }
  __syncthreads();
  const int ty = tid & 15, tx = tid >> 4;
  const int r0 = ty * 4, d0 = tx * 8;
  float acc[4][8];
#pragma unroll
  for (int rr = 0; rr < 4; ++rr)
#pragma unroll
    for (int dd = 0; dd < 8; ++dd) acc[rr][dd] = 0.f;
  for (int kk = 0; kk < 64; ++kk) {
    f32x4 w0 = *(const f32x4*)&wv[kk][d0];
    f32x4 w1 = *(const f32x4*)&wv[kk][d0 + 4];
    float cv[4];
#pragma unroll
    for (int rr = 0; rr < 4; ++rr) cv[rr] = ck[r0 + rr][kk];
#pragma unroll
    for (int rr = 0; rr < 4; ++rr)
#pragma unroll
      for (int e = 0; e < 4; ++e) {
        acc[rr][e] += cv[rr] * w0[e];
        acc[rr][4 + e] += cv[rr] * w1[e];
      }
  }
  float* obase = vT + (size_t)bh * 524288 + s0 + r0;
#pragma unroll
  for (int dd = 0; dd < 8; ++dd) {
    f32x4 pv;
    pv[0] = acc[0][dd]; pv[1] = acc[1][dd]; pv[2] = acc[2][dd]; pv[3] = acc[3][dd];
    *(f32x4*)(obase + (size_t)(d0 + dd) * 4096) = pv;
  }
}

// kv[f][d] = sum_s phi_k[s,f]*v[s,d], f32. grid (16 = fq*4+dq, 32 bh).
__global__ __launch_bounds__(256) void k_kvf2(const float* __restrict__ phikT,
                                              const float* __restrict__ vT,
                                              float* __restrict__ kvf) {
  const int fq = blockIdx.x >> 2, dq = blockIdx.x & 3, bh = blockIdx.y;
  const float* pT = phikT + (size_t)bh * 524288 + (size_t)fq * 32 * 4096;
  const float* vB = vT + (size_t)bh * 524288 + (size_t)dq * 32 * 4096;
  __shared__ float ps[64][33];
  __shared__ float vs[64][33];
  const int tid = threadIdx.x;
  const int fi = tid >> 3, d0 = (tid & 7) * 4;
  f32x4 acc = {0.f, 0.f, 0.f, 0.f};
  for (int ss = 0; ss < 4096; ss += 64) {
#pragma unroll
    for (int p = 0; p < 8; ++p) {
      int l = p * 256 + tid;
      int rr = l >> 6, si = l & 63;
      ps[si][rr] = pT[(size_t)rr * 4096 + ss + si];
      vs[si][rr] = vB[(size_t)rr * 4096 + ss + si];
    }
    __syncthreads();
    for (int si = 0; si < 64; ++si) {
      float pv = ps[si][fi];
#pragma unroll
      for (int j = 0; j < 4; ++j) acc[j] += pv * vs[si][d0 + j];
    }
    __syncthreads();
  }
  float* o = kvf + ((size_t)bh * 128 + fq * 32 + fi) * 128 + dq * 32 + d0;
  *(f32x4*)o = acc;
}

// Fused attention: phi_q + den (register-reduced) + num over all 128 d.
// grid (64 s-tiles, 64 bh).
__global__ __launch_bounds__(256) void k_attn2(const float* __restrict__ c,
                                               const float* __restrict__ wqp,
                                               const float* __restrict__ zb,
                                               const float* __restrict__ kvf,
                                               unsigned short* __restrict__ attn) {
  const int s0 = blockIdx.x * 64;
  const int bh = blockIdx.y;            // b*16 + head
  const int b = bh >> 4, hh = bh & 15;
  const int bhk = (b << 3) + (hh >> 1);
  __shared__ float wq[4096];
  __shared__ float cqt[64][33];
  __shared__ float phl[32][130];
  __shared__ float kvl[128][32];
  __shared__ float zl[128];
  __shared__ float denl[32];
  const int tid = threadIdx.x;
  if (tid < 128) zl[tid] = zb[bhk * 128 + tid];
#pragma unroll
  for (int p = 0; p < 16; ++p) wq[p * 256 + tid] = wqp[hh * 4096 + p * 256 + tid];
  const int fx = tid & 7, ty = tid >> 3;   // f0 = fx*8, token-row = ty (0..31)
  const int f0 = fx * 8;
  for (int hf = 0; hf < 2; ++hf) {
    __syncthreads();
#pragma unroll
    for (int p = 0; p < 8; ++p) {
      int l = p * 256 + tid;
      int sr = l >> 6, dd = l & 63;
      cqt[dd][sr] = c[(size_t)(b * 4096 + s0 + hf * 32 + sr) * 128 + dd];
    }
    __syncthreads();
    // proj for token ty, features f0..f0+7
    float pr[8];
#pragma unroll
    for (int ff = 0; ff < 8; ++ff) pr[ff] = 0.f;
    for (int dd = 0; dd < 64; ++dd) {
      f32x4 w0 = *(const f32x4*)(wq + dd * 64 + f0);
      f32x4 w1 = *(const f32x4*)(wq + dd * 64 + f0 + 4);
      float cv = cqt[dd][ty];
#pragma unroll
      for (int e = 0; e < 4; ++e) { pr[e] += cv * w0[e]; pr[4 + e] += cv * w1[e]; }
    }
    float dpart = 0.f;
#pragma unroll
    for (int ff = 0; ff < 8; ++ff) {
      float sv, cv;
      __sincosf(pr[ff], &sv, &cv);
      cv *= 0.125f; sv *= 0.125f;
      phl[ty][f0 + ff] = cv;
      phl[ty][64 + f0 + ff] = sv;
      dpart += cv * zl[f0 + ff] + sv * zl[64 + f0 + ff];
    }
    dpart += __shfl_down(dpart, 4);
    dpart += __shfl_down(dpart, 2);
    dpart += __shfl_down(dpart, 1);
    if (fx == 0) denl[ty] = dpart + 1e-6f;
    __syncthreads();
    for (int dq = 0; dq < 4; ++dq) {
#pragma unroll
      for (int p = 0; p < 16; ++p) {
        int l = p * 256 + tid;
        int f = l >> 5, j = l & 31;
        kvl[f][j] = kvf[(size_t)bhk * 16384 + (size_t)f * 128 + dq * 32 + j];
      }
      __syncthreads();
      const int row = tid >> 3, d0 = (tid & 7) * 4;
      f32x4 acc = {0.f, 0.f, 0.f, 0.f};
      for (int f = 0; f < 128; f += 2) {
        f32x2 pa = *(const f32x2*)&phl[row][f];
        f32x4 k0 = *(const f32x4*)&kvl[f][d0];
        f32x4 k1 = *(const f32x4*)&kvl[f + 1][d0];
#pragma unroll
        for (int j = 0; j < 4; ++j) acc[j] += pa[0] * k0[j] + pa[1] * k1[j];
      }
      const float dn = denl[row];
      u16x4 o4;
#pragma unroll
      for (int j = 0; j < 4; ++j) o4[j] = f2b(acc[j] / dn);
      *(u16x4*)(attn + (size_t)(b * 4096 + s0 + hf * 32 + row) * 2048 + hh * 128 + dq * 32 + d0) = o4;
      __syncthreads();
    }
  }
}

// LayerNorm bf16->bf16 (ln1)
__global__ __launch_bounds__(256) void k_ln_b2b(const unsigned short* __restrict__ in,
                                                const float* __restrict__ g,
                                                const float* __restrict__ bb,
                                                unsigned short* __restrict__ ob) {
  const int row = blockIdx.x;
  const unsigned short* xr = in + (size_t)row * 2048;
  float vals[8], s = 0.f, ss = 0.f;
#pragma unroll
  for (int i = 0; i < 8; ++i) {
    float v = b2f(xr[i * 256 + threadIdx.x]);
    vals[i] = v; s += v; ss += v * v;
  }
#pragma unroll
  for (int off = 32; off; off >>= 1) { s += __shfl_down(s, off); ss += __shfl_down(ss, off); }
  __shared__ float red[8];
  const int wave = threadIdx.x >> 6;
  if ((threadIdx.x & 63) == 0) { red[wave * 2] = s; red[wave * 2 + 1] = ss; }
  __syncthreads();
  float S = red[0] + red[2] + red[4] + red[6];
  float SS = red[1] + red[3] + red[5] + red[7];
  float mu = S * (1.f / 2048.f);
  float var = SS * (1.f / 2048.f) - mu * mu;
  float inv = rsqrtf(var + 1e-5f);
#pragma unroll
  for (int i = 0; i < 8; ++i) {
    int col = i * 256 + threadIdx.x;
    ob[(size_t)row * 2048 + col] = f2b((vals[i] - mu) * inv * g[col] + bb[col]);
  }
}

// In-place LayerNorm f32 (ln2 on out rows)
__global__ __launch_bounds__(256) void k_ln_ip(float* __restrict__ io,
                                               const float* __restrict__ g,
                                               const float* __restrict__ bb) {
  const int row = blockIdx.x;
  float* xr = io + (size_t)row * 2048;
  float vals[8], s = 0.f, ss = 0.f;
#pragma unroll
  for (int i = 0; i < 8; ++i) {
    float v = xr[i * 256 + threadIdx.x];
    vals[i] = v; s += v; ss += v * v;
  }
#pragma unroll
  for (int off = 32; off; off >>= 1) { s += __shfl_down(s, off); ss += __shfl_down(ss, off); }
  __shared__ float red[8];
  const int wave = threadIdx.x >> 6;
  if ((threadIdx.x & 63) == 0) { red[wave * 2] = s; red[wave * 2 + 1] = ss; }
  __syncthreads();
  float S = red[0] + red[2] + red[4] + red[6];
  float SS = red[1] + red[3] + red[5] + red[7];
  float mu = S * (1.f / 2048.f);
  float var = SS * (1.f / 2048.f) - mu * mu;
  float inv = rsqrtf(var + 1e-5f);
#pragma unroll
  for (int i = 0; i < 8; ++i) {
    int col = i * 256 + threadIdx.x;
    xr[col] = (vals[i] - mu) * inv * g[col] + bb[col];
  }
}

// ---------------------------------------------------------------------------
extern "C" void kernel_launch(void* const* d_in, const int* in_sizes, int n_in,
                              void* d_out, int out_size, void* d_ws, size_t ws_size,
                              hipStream_t stream) {
  (void)in_sizes; (void)n_in; (void)out_size; (void)ws_size;
  const float* x     = (const float*)d_in[0];
  const float* W_dq  = (const float*)d_in[1];
  const float* W_uq  = (const float*)d_in[2];
  const float* W_dkv = (const float*)d_in[3];
  const float* W_uk  = (const float*)d_in[4];
  const float* W_uv  = (const float*)d_in[5];
  const float* omega = (const float*)d_in[6];
  const float* W_o   = (const float*)d_in[7];
  const float* ln1g  = (const float*)d_in[8];
  const float* ln1b  = (const float*)d_in[9];
  const float* gateW = (const float*)d_in[10];
  const float* upW   = (const float*)d_in[11];
  const float* downW = (const float*)d_in[12];
  const float* ln2g  = (const float*)d_in[13];
  const float* ln2b  = (const float*)d_in[14];
  float* out = (float*)d_out;

  // Workspace (232 MiB, liveness-overlaid):
  // R0 [0,64M):    phikTf(f32) -> gatet|upt
  // R1 [64,128M):  vTf(f32) -> attn(bf16) -> hb(bf16)
  // R2 [128,192M): cbuf/wqp/wkp/zb/kvf -> y(bf16) -> act(64MB)
  // R3 [192,200M): wot   R4 [200,232M): downt
  char* w = (char*)d_ws;
  float*          phikTf = (float*)(w);
  float*          vTf    = (float*)(w + 67108864);
  unsigned short* attn   = (unsigned short*)(w + 67108864);
  unsigned short* hb     = (unsigned short*)(w + 67108864);
  unsigned short* gatet  = (unsigned short*)(w);
  unsigned short* upt    = (unsigned short*)(w + 33554432);
  char* C = w + 134217728;
  float*          cbuf = (float*)(C);
  float*          wqp  = (float*)(C + 8388608);
  float*          wkp  = (float*)(C + 8650752);
  float*          zb   = (float*)(C + 8781824);
  float*          kvf  = (float*)(C + 8798208);
  unsigned short* y    = (unsigned short*)(C);
  unsigned short* act  = (unsigned short*)(C);
  unsigned short* wot   = (unsigned short*)(w + 201326592);
  unsigned short* downt = (unsigned short*)(w + 209715200);

  // phase 0: prep
  k_zero<<<16, 256, 0, stream>>>(zb, 4096);
  k_wproj<<<24, 256, 0, stream>>>(W_uq, W_uk, omega, wqp, wkp);
  k_tc<<<dim3(32, 32), 256, 0, stream>>>(W_o, wot, 2048, 2048);

  // phase 1: latents (f32)
  k_cgemm<<<256, 256, 0, stream>>>(x, W_dq, W_dkv, cbuf);

  // phase 2: phi_k + z, v (f32)
  k_phikz<<<dim3(64, 32), 256, 0, stream>>>(cbuf, wkp, phikTf, zb);
  k_vf<<<dim3(64, 32), 256, 0, stream>>>(cbuf, W_uv, vTf);

  // phase 3: kv (f32), fused phi_q/den/num -> attn(bf16)
  k_kvf2<<<dim3(16, 32), 256, 0, stream>>>(phikTf, vTf, kvf);
  k_attn2<<<dim3(64, 64), 256, 0, stream>>>(cbuf, wqp, zb, kvf, attn);

  // phase 4: W_o + residual + LN1
  k_gemm_wo<<<dim3(128, 16), 256, 0, stream>>>(attn, wot, x, y);
  k_ln_b2b<<<16384, 256, 0, stream>>>(y, ln1g, ln1b, hb);

  // phase 5: FFN weight transposes into freed regions
  k_tc<<<dim3(128, 32), 256, 0, stream>>>(gateW, gatet, 2048, 8192);
  k_tc<<<dim3(128, 32), 256, 0, stream>>>(upW, upt, 2048, 8192);
  k_tc<<<dim3(32, 128), 256, 0, stream>>>(downW, downt, 8192, 2048);

  // phase 6: FFN in 4 chunks of 4096 rows; no gate buffer, LN2 in-place on out
  for (int cix = 0; cix < 4; ++cix) {
    const unsigned short* hbc = hb + (size_t)cix * 4096 * 2048;
    float* outc = out + (size_t)cix * 4096 * 2048;
    k_gemm_up2<<<dim3(32, 64), 256, 0, stream>>>(hbc, upt, act);
    k_gemm_gatem<<<dim3(32, 64), 256, 0, stream>>>(hbc, gatet, act);
    k_gemm_down2<<<dim3(32, 16), 256, 0, stream>>>(act, downt, hbc, outc);
    k_ln_ip<<<4096, 256, 0, stream>>>(outc, ln2g, ln2b);
  }
}